// Round 6
// baseline (584.844 us; speedup 1.0000x reference)
//
#include <hip/hip_runtime.h>

#define HD 4      // heads
#define DD 128    // model dim
#define CC 32     // channels per head

__device__ __forceinline__ void atomAddF(float* p, float v) {
#ifdef __HIP_PLATFORM_AMD__
    unsafeAtomicAdd(p, v);
#else
    atomicAdd(p, v);
#endif
}

// ---------------------------------------------------------------------------
// Precompute per-head weight column-sums and per-relation esum table.
// Wqh[l*512 + d*4 + h] = sum_c Wq[l][d][h*32+c]   (same for Wkh)
// esum[(l*R + r)*4 + h] = rel_emb[r] . Weh[l][:,h]
// ---------------------------------------------------------------------------
__global__ __launch_bounds__(256) void prep_kernel(
    const float* __restrict__ Wq, const float* __restrict__ Wk,
    const float* __restrict__ We, const float* __restrict__ rel,
    float* __restrict__ Wqh, float* __restrict__ Wkh,
    float* __restrict__ esum, int R)
{
    __shared__ float WehS[2][DD][HD];   // 4 KB
    int tid = threadIdx.x;
    for (int i = tid; i < 2 * DD * HD; i += 256) {
        int l = i / (DD * HD);
        int d = (i / HD) % DD;
        int h = i % HD;
        const float* bq = Wq + ((size_t)l * DD + d) * DD + h * CC;
        const float* bk = Wk + ((size_t)l * DD + d) * DD + h * CC;
        const float* be = We + ((size_t)l * DD + d) * DD + h * CC;
        float sq = 0.f, sk = 0.f, se = 0.f;
        for (int c = 0; c < CC; ++c) { sq += bq[c]; sk += bk[c]; se += be[c]; }
        Wqh[i] = sq; Wkh[i] = sk; WehS[l][d][h] = se;
    }
    __syncthreads();
    for (int i = tid; i < 2 * R * HD; i += 256) {
        int l = i / (R * HD);
        int r = (i / HD) % R;
        int h = i % HD;
        const float* rp = rel + (size_t)r * DD;
        float a = 0.f;
        for (int d = 0; d < DD; ++d) a += rp[d] * WehS[l][d][h];
        esum[i] = a;
    }
}

// ---------------------------------------------------------------------------
// C[M x 128] = gather(A)[M x K] @ B[K x 128] (+bias). Tiled fp32 GEMM.
// Block: 256 thr, 64-row x 128-col tile, per-thread 8x4 register tile.
// ---------------------------------------------------------------------------
__global__ __launch_bounds__(256) void gemm128(
    const float* __restrict__ A, const int* __restrict__ gather,
    const float* __restrict__ B, const float* __restrict__ bias,
    float* __restrict__ C, int M, int K)
{
    __shared__ float As[16][68];    // A^T tile, padded (68*4B = 17*16B: f4-aligned)
    __shared__ float Bs[16][132];   // padded     (132*4B = 33*16B: f4-aligned)
    const int tid = threadIdx.x;
    const int row0 = blockIdx.x * 64;
    const int ty = tid >> 5, tx = tid & 31;
    float acc[8][4] = {};

    // A-load mapping: 4 threads per row, float4 each
    const int ar = tid >> 2;           // 0..63 tile row
    const int ak = (tid & 3) * 4;      // 0,4,8,12 within 16-wide k chunk
    int arow = row0 + ar; if (arow >= M) arow = M - 1;
    const int grow = gather ? gather[arow] : arow;
    const float* Ap = A + (size_t)grow * K;
    // B-load mapping: 16 threads per k-row, 8 floats each
    const int bk = tid >> 4;           // 0..15
    const int bc = (tid & 15) * 8;     // 0..120

    for (int k0 = 0; k0 < K; k0 += 16) {
        float4 av = *(const float4*)(Ap + k0 + ak);
        float4 b0 = *(const float4*)(B + (size_t)(k0 + bk) * DD + bc);
        float4 b1 = *(const float4*)(B + (size_t)(k0 + bk) * DD + bc + 4);
        __syncthreads();
        As[ak + 0][ar] = av.x; As[ak + 1][ar] = av.y;
        As[ak + 2][ar] = av.z; As[ak + 3][ar] = av.w;
        *(float4*)&Bs[bk][bc]     = b0;
        *(float4*)&Bs[bk][bc + 4] = b1;
        __syncthreads();
#pragma unroll
        for (int kk = 0; kk < 16; ++kk) {
            const float4 a0 = *(const float4*)&As[kk][ty * 8];
            const float4 a1 = *(const float4*)&As[kk][ty * 8 + 4];
            const float4 bv = *(const float4*)&Bs[kk][tx * 4];
            float a[8] = {a0.x, a0.y, a0.z, a0.w, a1.x, a1.y, a1.z, a1.w};
            float b[4] = {bv.x, bv.y, bv.z, bv.w};
#pragma unroll
            for (int i = 0; i < 8; ++i)
#pragma unroll
                for (int j = 0; j < 4; ++j) acc[i][j] += a[i] * b[j];
        }
    }
    float bv[4] = {0.f, 0.f, 0.f, 0.f};
    if (bias) {
        bv[0] = bias[tx * 4 + 0]; bv[1] = bias[tx * 4 + 1];
        bv[2] = bias[tx * 4 + 2]; bv[3] = bias[tx * 4 + 3];
    }
#pragma unroll
    for (int i = 0; i < 8; ++i) {
        int row = row0 + ty * 8 + i;
        if (row < M) {
            float4 r;
            r.x = acc[i][0] + bv[0]; r.y = acc[i][1] + bv[1];
            r.z = acc[i][2] + bv[2]; r.w = acc[i][3] + bv[3];
            *(float4*)&C[(size_t)row * DD + tx * 4] = r;
        }
    }
}

// ---------------------------------------------------------------------------
// qsum/ksum: per node, per head: x[n,:] . Wqh[:,h]  (64 rows per block)
// ---------------------------------------------------------------------------
__global__ __launch_bounds__(256) void qk_sums(
    const float* __restrict__ x, const float* __restrict__ Wqh,
    const float* __restrict__ Wkh, float* __restrict__ qs,
    float* __restrict__ ks, int N)
{
    __shared__ float xs[64][132];       // padded: bank-conflict-free column reads
    __shared__ float wq[DD * HD], wk[DD * HD];
    int tid = threadIdx.x;
    int row0 = blockIdx.x * 64;
    for (int i = tid; i < DD * HD; i += 256) { wq[i] = Wqh[i]; wk[i] = Wkh[i]; }
    int lr = tid >> 2;              // 0..63
    int lq = (tid & 3) * 32;        // quarter of the row
    int srow = row0 + lr; if (srow >= N) srow = N - 1;
    const float* xp = x + (size_t)srow * DD + lq;
#pragma unroll
    for (int j = 0; j < 8; ++j) {
        float4 vv = *(const float4*)(xp + j * 4);
        *(float4*)&xs[lr][lq + j * 4] = vv;
    }
    __syncthreads();
    int r = tid >> 2, h = tid & 3;
    float aq = 0.f, ak = 0.f;
    for (int d = 0; d < DD; ++d) {
        float xv = xs[r][d];
        aq += xv * wq[d * HD + h];
        ak += xv * wk[d * HD + h];
    }
    int row = row0 + r;
    if (row < N) { qs[row * HD + h] = aq; ks[row * HD + h] = ak; }
}

// ---------------------------------------------------------------------------
// Edge pass 1: ex = exp(leaky_relu(alpha)); accumulate softmax denominator.
// One thread per (edge, head).
// ---------------------------------------------------------------------------
__global__ __launch_bounds__(256) void edge_alpha(
    const int* __restrict__ srcv, const int* __restrict__ dstv,
    const int* __restrict__ et, const float* __restrict__ ew,
    const float* __restrict__ qs, const float* __restrict__ ks,
    const float* __restrict__ esum, const float* __restrict__ gate,
    float* __restrict__ exb, float* __restrict__ sden, int E)
{
    int t = blockIdx.x * 256 + threadIdx.x;
    if (t >= E * HD) return;
    int e = t >> 2, h = t & 3;
    int d = dstv[e], sr = srcv[e], r = et[e];
    float a = (qs[d * HD + h] + ks[sr * HD + h] + esum[r * HD + h]) * 0.17677669529663687f
              + gate[h] * ew[e];
    a = a > 0.f ? a : 0.2f * a;             // leaky_relu(0.2)
    float x = __expf(a);                    // no max-subtraction needed: |a| small
    exb[t] = x;
    atomAddF(&sden[d * HD + h], x);
}

// ---------------------------------------------------------------------------
// Edge pass 2: acc[dst,:] += ex * v[src,:]. One thread per (edge, channel).
// ---------------------------------------------------------------------------
__global__ __launch_bounds__(256) void edge_msg(
    const int* __restrict__ srcv, const int* __restrict__ dstv,
    const float* __restrict__ exb, const float* __restrict__ v,
    float* __restrict__ acc, int E)
{
    int t = blockIdx.x * 256 + threadIdx.x;
    if (t >= E * DD) return;                 // 51.2M < 2^31
    int e = t >> 7, c = t & 127, h = c >> 5;
    int sr = srcv[e], d = dstv[e];
    float val = exb[e * HD + h] * v[(size_t)sr * DD + c];
    atomAddF(&acc[(size_t)d * DD + c], val);
}

// ---------------------------------------------------------------------------
// Node epilogue: divide by denom, add bias, optional ELU.
// ---------------------------------------------------------------------------
__global__ __launch_bounds__(256) void node_out(
    const float* __restrict__ acc, const float* __restrict__ sden,
    const float* __restrict__ bias, float* __restrict__ xout,
    int N, int do_elu)
{
    int t = blockIdx.x * 256 + threadIdx.x;
    if (t >= N * DD) return;
    int n = t >> 7, c = t & 127, h = c >> 5;
    float z = acc[t] / (sden[n * HD + h] + 1e-16f) + bias[c];
    if (do_elu) z = z > 0.f ? z : expm1f(z);
    xout[t] = z;
}

// ---------------------------------------------------------------------------
extern "C" void kernel_launch(void* const* d_in, const int* in_sizes, int n_in,
                              void* d_out, int out_size, void* d_ws, size_t ws_size,
                              hipStream_t stream)
{
    const int*   entity = (const int*)d_in[0];
    const int*   eidx   = (const int*)d_in[1];
    const int*   etype  = (const int*)d_in[2];
    const float* ew     = (const float*)d_in[3];
    const float* ent    = (const float*)d_in[4];
    const float* pw     = (const float*)d_in[5];
    const float* pb     = (const float*)d_in[6];
    const float* rel    = (const float*)d_in[7];
    const float* Wq     = (const float*)d_in[8];
    const float* Wk     = (const float*)d_in[9];
    const float* Wv     = (const float*)d_in[10];
    const float* We     = (const float*)d_in[11];
    const float* gate   = (const float*)d_in[12];
    const float* cb     = (const float*)d_in[13];

    const int N = in_sizes[0];
    const int E = in_sizes[2];
    const int F = in_sizes[4] / N;     // 256
    const int R = in_sizes[7] / DD;    // 200

    const int* srcv = eidx;
    const int* dstv = eidx + E;

    float* ws = (float*)d_ws;
    size_t o = 0;
    float* xbuf = ws + o; o += (size_t)N * DD;     // current x
    float* vbuf = ws + o; o += (size_t)N * DD;     // v = x @ Wv
    float* qs   = ws + o; o += (size_t)N * HD;
    float* ks   = ws + o; o += (size_t)N * HD;
    float* sden = ws + o; o += (size_t)N * HD;
    float* exb  = ws + o; o += (size_t)E * HD;
    float* Wqh  = ws + o; o += 2 * DD * HD;
    float* Wkh  = ws + o; o += 2 * DD * HD;
    float* esum = ws + o; o += (size_t)2 * R * HD;
    float* accb = (float*)d_out;                   // numerator accumulator

    prep_kernel<<<1, 256, 0, stream>>>(Wq, Wk, We, rel, Wqh, Wkh, esum, R);

    const int gblk = (N + 63) / 64;
    // x0 = ent_table[entity] @ proj_w + proj_b
    gemm128<<<gblk, 256, 0, stream>>>(ent, entity, pw, pb, xbuf, N, F);

    for (int l = 0; l < 2; ++l) {
        gemm128<<<gblk, 256, 0, stream>>>(xbuf, nullptr, Wv + (size_t)l * DD * DD,
                                          nullptr, vbuf, N, DD);
        qk_sums<<<gblk, 256, 0, stream>>>(xbuf, Wqh + l * DD * HD, Wkh + l * DD * HD,
                                          qs, ks, N);
        hipMemsetAsync(accb, 0, (size_t)N * DD * sizeof(float), stream);
        hipMemsetAsync(sden, 0, (size_t)N * HD * sizeof(float), stream);
        edge_alpha<<<(E * HD + 255) / 256, 256, 0, stream>>>(
            srcv, dstv, etype, ew, qs, ks, esum + (size_t)l * R * HD,
            gate + l * HD, exb, sden, E);
        edge_msg<<<(int)(((size_t)E * DD + 255) / 256), 256, 0, stream>>>(
            srcv, dstv, exb, vbuf, accb, E);
        node_out<<<(N * DD + 255) / 256, 256, 0, stream>>>(
            accb, sden, cb + l * DD, (l == 0) ? xbuf : accb, N, (l == 0) ? 1 : 0);
    }
}

// Round 7
// 409.835 us; speedup vs baseline: 1.4270x; 1.4270x over previous
//
#include <hip/hip_runtime.h>

#define HD 4      // heads
#define DD 128    // model dim
#define CC 32     // channels per head

// ---------------------------------------------------------------------------
// Precompute per-head weight column-sums and per-relation esum table.
// Wqh[l*512 + d*4 + h] = sum_c Wq[l][d][h*32+c]   (same for Wkh)
// esum[(l*R + r)*4 + h] = rel_emb[r] . Weh[l][:,h]
// ---------------------------------------------------------------------------
__global__ __launch_bounds__(256) void prep_kernel(
    const float* __restrict__ Wq, const float* __restrict__ Wk,
    const float* __restrict__ We, const float* __restrict__ rel,
    float* __restrict__ Wqh, float* __restrict__ Wkh,
    float* __restrict__ esum, int R)
{
    __shared__ float WehS[2][DD][HD];   // 4 KB
    int tid = threadIdx.x;
    for (int i = tid; i < 2 * DD * HD; i += 256) {
        int l = i / (DD * HD);
        int d = (i / HD) % DD;
        int h = i % HD;
        const float* bq = Wq + ((size_t)l * DD + d) * DD + h * CC;
        const float* bk = Wk + ((size_t)l * DD + d) * DD + h * CC;
        const float* be = We + ((size_t)l * DD + d) * DD + h * CC;
        float sq = 0.f, sk = 0.f, se = 0.f;
        for (int c = 0; c < CC; ++c) { sq += bq[c]; sk += bk[c]; se += be[c]; }
        Wqh[i] = sq; Wkh[i] = sk; WehS[l][d][h] = se;
    }
    __syncthreads();
    for (int i = tid; i < 2 * R * HD; i += 256) {
        int l = i / (R * HD);
        int r = (i / HD) % R;
        int h = i % HD;
        const float* rp = rel + (size_t)r * DD;
        float a = 0.f;
        for (int d = 0; d < DD; ++d) a += rp[d] * WehS[l][d][h];
        esum[i] = a;
    }
}

// ---------------------------------------------------------------------------
// C[M x 128] = gather(A)[M x K] @ B[K x 128] (+bias). Tiled fp32 GEMM.
// ---------------------------------------------------------------------------
__global__ __launch_bounds__(256) void gemm128(
    const float* __restrict__ A, const int* __restrict__ gather,
    const float* __restrict__ B, const float* __restrict__ bias,
    float* __restrict__ C, int M, int K)
{
    __shared__ float As[16][68];
    __shared__ float Bs[16][132];
    const int tid = threadIdx.x;
    const int row0 = blockIdx.x * 64;
    const int ty = tid >> 5, tx = tid & 31;
    float acc[8][4] = {};

    const int ar = tid >> 2;
    const int ak = (tid & 3) * 4;
    int arow = row0 + ar; if (arow >= M) arow = M - 1;
    const int grow = gather ? gather[arow] : arow;
    const float* Ap = A + (size_t)grow * K;
    const int bk = tid >> 4;
    const int bc = (tid & 15) * 8;

    for (int k0 = 0; k0 < K; k0 += 16) {
        float4 av = *(const float4*)(Ap + k0 + ak);
        float4 b0 = *(const float4*)(B + (size_t)(k0 + bk) * DD + bc);
        float4 b1 = *(const float4*)(B + (size_t)(k0 + bk) * DD + bc + 4);
        __syncthreads();
        As[ak + 0][ar] = av.x; As[ak + 1][ar] = av.y;
        As[ak + 2][ar] = av.z; As[ak + 3][ar] = av.w;
        *(float4*)&Bs[bk][bc]     = b0;
        *(float4*)&Bs[bk][bc + 4] = b1;
        __syncthreads();
#pragma unroll
        for (int kk = 0; kk < 16; ++kk) {
            const float4 a0 = *(const float4*)&As[kk][ty * 8];
            const float4 a1 = *(const float4*)&As[kk][ty * 8 + 4];
            const float4 bv = *(const float4*)&Bs[kk][tx * 4];
            float a[8] = {a0.x, a0.y, a0.z, a0.w, a1.x, a1.y, a1.z, a1.w};
            float b[4] = {bv.x, bv.y, bv.z, bv.w};
#pragma unroll
            for (int i = 0; i < 8; ++i)
#pragma unroll
                for (int j = 0; j < 4; ++j) acc[i][j] += a[i] * b[j];
        }
    }
    float bv[4] = {0.f, 0.f, 0.f, 0.f};
    if (bias) {
        bv[0] = bias[tx * 4 + 0]; bv[1] = bias[tx * 4 + 1];
        bv[2] = bias[tx * 4 + 2]; bv[3] = bias[tx * 4 + 3];
    }
#pragma unroll
    for (int i = 0; i < 8; ++i) {
        int row = row0 + ty * 8 + i;
        if (row < M) {
            float4 r;
            r.x = acc[i][0] + bv[0]; r.y = acc[i][1] + bv[1];
            r.z = acc[i][2] + bv[2]; r.w = acc[i][3] + bv[3];
            *(float4*)&C[(size_t)row * DD + tx * 4] = r;
        }
    }
}

// ---------------------------------------------------------------------------
// qsum/ksum: per node, per head: x[n,:] . Wqh[:,h]
// ---------------------------------------------------------------------------
__global__ __launch_bounds__(256) void qk_sums(
    const float* __restrict__ x, const float* __restrict__ Wqh,
    const float* __restrict__ Wkh, float* __restrict__ qs,
    float* __restrict__ ks, int N)
{
    __shared__ float xs[64][132];
    __shared__ float wq[DD * HD], wk[DD * HD];
    int tid = threadIdx.x;
    int row0 = blockIdx.x * 64;
    for (int i = tid; i < DD * HD; i += 256) { wq[i] = Wqh[i]; wk[i] = Wkh[i]; }
    int lr = tid >> 2;
    int lq = (tid & 3) * 32;
    int srow = row0 + lr; if (srow >= N) srow = N - 1;
    const float* xp = x + (size_t)srow * DD + lq;
#pragma unroll
    for (int j = 0; j < 8; ++j) {
        float4 vv = *(const float4*)(xp + j * 4);
        *(float4*)&xs[lr][lq + j * 4] = vv;
    }
    __syncthreads();
    int r = tid >> 2, h = tid & 3;
    float aq = 0.f, ak = 0.f;
    for (int d = 0; d < DD; ++d) {
        float xv = xs[r][d];
        aq += xv * wq[d * HD + h];
        ak += xv * wk[d * HD + h];
    }
    int row = row0 + r;
    if (row < N) { qs[row * HD + h] = aq; ks[row * HD + h] = ak; }
}

// ---------------------------------------------------------------------------
// CSR build: histogram, single-block scan, scatter (order nondeterministic
// within a node — only permutes fp-add order, ~1e-6 jitter, threshold 5e-2).
// ---------------------------------------------------------------------------
__global__ __launch_bounds__(256) void csr_count(
    const int* __restrict__ dstv, int* __restrict__ deg, int E)
{
    int t = blockIdx.x * 256 + threadIdx.x;
    if (t < E) atomicAdd(&deg[dstv[t]], 1);
}

__global__ __launch_bounds__(1024) void csr_scan(
    const int* __restrict__ deg, int* __restrict__ row_ptr, int N)
{
    __shared__ int sums[1024];
    int tid = threadIdx.x;
    int chunk = (N + 1023) / 1024;
    int b = tid * chunk, e = b + chunk; if (e > N) e = N;
    int s = 0;
    for (int i = b; i < e && i < N; ++i) s += deg[i];
    sums[tid] = s;
    __syncthreads();
    for (int off = 1; off < 1024; off <<= 1) {
        int v = (tid >= off) ? sums[tid - off] : 0;
        __syncthreads();
        sums[tid] += v;
        __syncthreads();
    }
    int base = (tid == 0) ? 0 : sums[tid - 1];
    for (int i = b; i < e && i < N; ++i) { row_ptr[i] = base; base += deg[i]; }
    if (tid == 1023) row_ptr[N] = sums[1023];
}

__global__ __launch_bounds__(256) void csr_scatter(
    const int* __restrict__ srcv, const int* __restrict__ dstv,
    const int* __restrict__ etype, const float* __restrict__ ew,
    const int* __restrict__ row_ptr, int* __restrict__ cursor,
    int* __restrict__ c_src, int* __restrict__ c_et, float* __restrict__ c_ew,
    int E)
{
    int e = blockIdx.x * 256 + threadIdx.x;
    if (e >= E) return;
    int d = dstv[e];
    int p = row_ptr[d] + atomicAdd(&cursor[d], 1);
    c_src[p] = srcv[e];
    c_et[p]  = etype[e];
    c_ew[p]  = ew[e];
}

// ---------------------------------------------------------------------------
// Fused per-layer edge+softmax+aggregate+epilogue. One wave per dst node.
// Lane l owns channels {2l, 2l+1} (head h = l>>4). All lanes redundantly
// compute the 4 per-head alphas (wave-uniform loads broadcast from L1);
// numerator and denominator accumulate in registers; single coalesced
// 512 B row write. No atomics anywhere.
// ---------------------------------------------------------------------------
__global__ __launch_bounds__(256) void fused_conv(
    const int* __restrict__ row_ptr, const int* __restrict__ c_src,
    const int* __restrict__ c_et, const float* __restrict__ c_ew,
    const float* __restrict__ qs, const float* __restrict__ ks,
    const float* __restrict__ esum, const float* __restrict__ gate,
    const float* __restrict__ v, const float* __restrict__ bias,
    float* __restrict__ out, int N, int do_elu)
{
    int gw = (blockIdx.x * 256 + threadIdx.x) >> 6;   // global wave id = node
    int lane = threadIdx.x & 63;
    if (gw >= N) return;
    const int n = gw;
    const int beg = row_ptr[n], end = row_ptr[n + 1];
    const float4 qv = *(const float4*)&qs[(size_t)n * 4];
    const float4 gv = *(const float4*)gate;
    const int c0 = lane * 2;
    const int h = lane >> 4;          // head of channels 2l, 2l+1
    const float sc = 0.17677669529663687f;   // 1/sqrt(32)

    float num0 = 0.f, num1 = 0.f;
    float den0 = 0.f, den1 = 0.f, den2 = 0.f, den3 = 0.f;

    for (int j = beg; j < end; ++j) {
        int s   = c_src[j];
        int r   = c_et[j];
        float w = c_ew[j];
        float4 kv = *(const float4*)&ks[(size_t)s * 4];
        float4 ev = *(const float4*)&esum[(size_t)r * 4];
        float a0 = (qv.x + kv.x + ev.x) * sc + gv.x * w;
        float a1 = (qv.y + kv.y + ev.y) * sc + gv.y * w;
        float a2 = (qv.z + kv.z + ev.z) * sc + gv.z * w;
        float a3 = (qv.w + kv.w + ev.w) * sc + gv.w * w;
        a0 = a0 > 0.f ? a0 : 0.2f * a0;     // leaky_relu(0.2)
        a1 = a1 > 0.f ? a1 : 0.2f * a1;
        a2 = a2 > 0.f ? a2 : 0.2f * a2;
        a3 = a3 > 0.f ? a3 : 0.2f * a3;
        float e0 = __expf(a0), e1 = __expf(a1);
        float e2 = __expf(a2), e3 = __expf(a3);
        den0 += e0; den1 += e1; den2 += e2; den3 += e3;
        float ex = (h == 0) ? e0 : (h == 1) ? e1 : (h == 2) ? e2 : e3;
        float2 vv = *(const float2*)&v[(size_t)s * DD + c0];
        num0 += ex * vv.x;
        num1 += ex * vv.y;
    }

    float den = (h == 0) ? den0 : (h == 1) ? den1 : (h == 2) ? den2 : den3;
    float inv = 1.f / (den + 1e-16f);
    float r0 = num0 * inv + bias[c0];
    float r1 = num1 * inv + bias[c0 + 1];
    if (do_elu) {
        r0 = r0 > 0.f ? r0 : expm1f(r0);
        r1 = r1 > 0.f ? r1 : expm1f(r1);
    }
    *(float2*)&out[(size_t)n * DD + c0] = make_float2(r0, r1);
}

// ---------------------------------------------------------------------------
extern "C" void kernel_launch(void* const* d_in, const int* in_sizes, int n_in,
                              void* d_out, int out_size, void* d_ws, size_t ws_size,
                              hipStream_t stream)
{
    const int*   entity = (const int*)d_in[0];
    const int*   eidx   = (const int*)d_in[1];
    const int*   etype  = (const int*)d_in[2];
    const float* ew     = (const float*)d_in[3];
    const float* ent    = (const float*)d_in[4];
    const float* pw     = (const float*)d_in[5];
    const float* pb     = (const float*)d_in[6];
    const float* rel    = (const float*)d_in[7];
    const float* Wq     = (const float*)d_in[8];
    const float* Wk     = (const float*)d_in[9];
    const float* Wv     = (const float*)d_in[10];
    const float* We     = (const float*)d_in[11];
    const float* gate   = (const float*)d_in[12];
    const float* cb     = (const float*)d_in[13];

    const int N = in_sizes[0];
    const int E = in_sizes[2];
    const int F = in_sizes[4] / N;     // 256
    const int R = in_sizes[7] / DD;    // 200

    const int* srcv = eidx;
    const int* dstv = eidx + E;

    float* ws = (float*)d_ws;
    size_t o = 0;
    float* xbuf    = ws + o; o += (size_t)N * DD;
    float* vbuf    = ws + o; o += (size_t)N * DD;
    float* qs      = ws + o; o += (size_t)N * HD;
    float* ks      = ws + o; o += (size_t)N * HD;
    float* Wqh     = ws + o; o += 2 * DD * HD;
    float* Wkh     = ws + o; o += 2 * DD * HD;
    float* esum    = ws + o; o += (size_t)2 * R * HD;
    int*   deg     = (int*)(ws + o); o += N;          // also doubles as scratch
    int*   cursor  = (int*)(ws + o); o += N;
    int*   row_ptr = (int*)(ws + o); o += (size_t)N + 1;
    int*   c_src   = (int*)(ws + o); o += E;
    int*   c_et    = (int*)(ws + o); o += E;
    float* c_ew    = ws + o;         o += E;

    prep_kernel<<<1, 256, 0, stream>>>(Wq, Wk, We, rel, Wqh, Wkh, esum, R);

    // CSR build (layer-independent, built once)
    hipMemsetAsync(deg, 0, (size_t)2 * N * sizeof(int), stream);  // deg + cursor
    csr_count<<<(E + 255) / 256, 256, 0, stream>>>(dstv, deg, E);
    csr_scan<<<1, 1024, 0, stream>>>(deg, row_ptr, N);
    csr_scatter<<<(E + 255) / 256, 256, 0, stream>>>(
        srcv, dstv, etype, ew, row_ptr, cursor, c_src, c_et, c_ew, E);

    const int gblk = (N + 63) / 64;
    // x0 = ent_table[entity] @ proj_w + proj_b
    gemm128<<<gblk, 256, 0, stream>>>(ent, entity, pw, pb, xbuf, N, F);

    const int fblk = (N + 3) / 4;     // one 64-lane wave per node
    for (int l = 0; l < 2; ++l) {
        gemm128<<<gblk, 256, 0, stream>>>(xbuf, nullptr, Wv + (size_t)l * DD * DD,
                                          nullptr, vbuf, N, DD);
        qk_sums<<<gblk, 256, 0, stream>>>(xbuf, Wqh + l * DD * HD, Wkh + l * DD * HD,
                                          qs, ks, N);
        fused_conv<<<fblk, 256, 0, stream>>>(
            row_ptr, c_src, c_et, c_ew, qs, ks, esum + (size_t)l * R * HD,
            gate + l * HD, vbuf, cb + l * DD,
            (l == 0) ? xbuf : (float*)d_out, N, (l == 0) ? 1 : 0);
    }
}

// Round 10
// 344.026 us; speedup vs baseline: 1.7000x; 1.1913x over previous
//
#include <hip/hip_runtime.h>

#define HD 4      // heads
#define DD 128    // model dim
#define CC 32     // channels per head
#define SCAN_B 64
#define SCAN_T 256

// ---------------------------------------------------------------------------
// Precompute per-head weight column-sums and per-relation esum table.
// Wqh[l*512 + d*4 + h] = sum_c Wq[l][d][h*32+c]   (same for Wkh)
// esum[(l*R + r)*4 + h] = rel_emb[r] . Weh[l][:,h]
// ---------------------------------------------------------------------------
__global__ __launch_bounds__(256) void prep_kernel(
    const float* __restrict__ Wq, const float* __restrict__ Wk,
    const float* __restrict__ We, const float* __restrict__ rel,
    float* __restrict__ Wqh, float* __restrict__ Wkh,
    float* __restrict__ esum, int R)
{
    __shared__ float WehS[2][DD][HD];   // 4 KB
    int tid = threadIdx.x;
    for (int i = tid; i < 2 * DD * HD; i += 256) {
        int l = i / (DD * HD);
        int d = (i / HD) % DD;
        int h = i % HD;
        const float* bq = Wq + ((size_t)l * DD + d) * DD + h * CC;
        const float* bk = Wk + ((size_t)l * DD + d) * DD + h * CC;
        const float* be = We + ((size_t)l * DD + d) * DD + h * CC;
        float sq = 0.f, sk = 0.f, se = 0.f;
        for (int c = 0; c < CC; ++c) { sq += bq[c]; sk += bk[c]; se += be[c]; }
        Wqh[i] = sq; Wkh[i] = sk; WehS[l][d][h] = se;
    }
    __syncthreads();
    for (int i = tid; i < 2 * R * HD; i += 256) {
        int l = i / (R * HD);
        int r = (i / HD) % R;
        int h = i % HD;
        const float* rp = rel + (size_t)r * DD;
        float a = 0.f;
        for (int d = 0; d < DD; ++d) a += rp[d] * WehS[l][d][h];
        esum[i] = a;
    }
}

// ---------------------------------------------------------------------------
// C[M x 128] = gather(A)[M x K] @ B[K x 128] (+bias). Tiled fp32 GEMM.
// ---------------------------------------------------------------------------
__global__ __launch_bounds__(256) void gemm128(
    const float* __restrict__ A, const int* __restrict__ gather,
    const float* __restrict__ B, const float* __restrict__ bias,
    float* __restrict__ C, int M, int K)
{
    __shared__ float As[16][68];
    __shared__ float Bs[16][132];
    const int tid = threadIdx.x;
    const int row0 = blockIdx.x * 64;
    const int ty = tid >> 5, tx = tid & 31;
    float acc[8][4] = {};

    const int ar = tid >> 2;
    const int ak = (tid & 3) * 4;
    int arow = row0 + ar; if (arow >= M) arow = M - 1;
    const int grow = gather ? gather[arow] : arow;
    const float* Ap = A + (size_t)grow * K;
    const int bk = tid >> 4;
    const int bc = (tid & 15) * 8;

    for (int k0 = 0; k0 < K; k0 += 16) {
        float4 av = *(const float4*)(Ap + k0 + ak);
        float4 b0 = *(const float4*)(B + (size_t)(k0 + bk) * DD + bc);
        float4 b1 = *(const float4*)(B + (size_t)(k0 + bk) * DD + bc + 4);
        __syncthreads();
        As[ak + 0][ar] = av.x; As[ak + 1][ar] = av.y;
        As[ak + 2][ar] = av.z; As[ak + 3][ar] = av.w;
        *(float4*)&Bs[bk][bc]     = b0;
        *(float4*)&Bs[bk][bc + 4] = b1;
        __syncthreads();
#pragma unroll
        for (int kk = 0; kk < 16; ++kk) {
            const float4 a0 = *(const float4*)&As[kk][ty * 8];
            const float4 a1 = *(const float4*)&As[kk][ty * 8 + 4];
            const float4 bv = *(const float4*)&Bs[kk][tx * 4];
            float a[8] = {a0.x, a0.y, a0.z, a0.w, a1.x, a1.y, a1.z, a1.w};
            float b[4] = {bv.x, bv.y, bv.z, bv.w};
#pragma unroll
            for (int i = 0; i < 8; ++i)
#pragma unroll
                for (int j = 0; j < 4; ++j) acc[i][j] += a[i] * b[j];
        }
    }
    float bv[4] = {0.f, 0.f, 0.f, 0.f};
    if (bias) {
        bv[0] = bias[tx * 4 + 0]; bv[1] = bias[tx * 4 + 1];
        bv[2] = bias[tx * 4 + 2]; bv[3] = bias[tx * 4 + 3];
    }
#pragma unroll
    for (int i = 0; i < 8; ++i) {
        int row = row0 + ty * 8 + i;
        if (row < M) {
            float4 r;
            r.x = acc[i][0] + bv[0]; r.y = acc[i][1] + bv[1];
            r.z = acc[i][2] + bv[2]; r.w = acc[i][3] + bv[3];
            *(float4*)&C[(size_t)row * DD + tx * 4] = r;
        }
    }
}

// ---------------------------------------------------------------------------
// qsum/ksum: per node, per head: x[n,:] . Wqh[:,h]
// ---------------------------------------------------------------------------
__global__ __launch_bounds__(256) void qk_sums(
    const float* __restrict__ x, const float* __restrict__ Wqh,
    const float* __restrict__ Wkh, float* __restrict__ qs,
    float* __restrict__ ks, int N)
{
    __shared__ float xs[64][132];
    __shared__ float wq[DD * HD], wk[DD * HD];
    int tid = threadIdx.x;
    int row0 = blockIdx.x * 64;
    for (int i = tid; i < DD * HD; i += 256) { wq[i] = Wqh[i]; wk[i] = Wkh[i]; }
    int lr = tid >> 2;
    int lq = (tid & 3) * 32;
    int srow = row0 + lr; if (srow >= N) srow = N - 1;
    const float* xp = x + (size_t)srow * DD + lq;
#pragma unroll
    for (int j = 0; j < 8; ++j) {
        float4 vv = *(const float4*)(xp + j * 4);
        *(float4*)&xs[lr][lq + j * 4] = vv;
    }
    __syncthreads();
    int r = tid >> 2, h = tid & 3;
    float aq = 0.f, ak = 0.f;
    for (int d = 0; d < DD; ++d) {
        float xv = xs[r][d];
        aq += xv * wq[d * HD + h];
        ak += xv * wk[d * HD + h];
    }
    int row = row0 + r;
    if (row < N) { qs[row * HD + h] = aq; ks[row * HD + h] = ak; }
}

// ---------------------------------------------------------------------------
// CSR build: histogram + hierarchical 3-kernel scan + scatter.
// (scatter order nondeterministic within a node — only permutes fp-add
//  order, ~1e-6 jitter vs 5e-2 threshold)
// ---------------------------------------------------------------------------
__global__ __launch_bounds__(256) void csr_count(
    const int* __restrict__ dstv, int* __restrict__ deg, int E)
{
    int t = blockIdx.x * 256 + threadIdx.x;
    if (t < E) atomicAdd(&deg[dstv[t]], 1);
}

// k1: per-block chunk reduction -> blksum[b]
__global__ __launch_bounds__(SCAN_T) void scan_partial(
    const int* __restrict__ deg, int* __restrict__ blksum, int N)
{
    __shared__ int red[SCAN_T];
    int chunk = (N + SCAN_B - 1) / SCAN_B;
    int b0 = blockIdx.x * chunk;
    int e0 = b0 + chunk; if (e0 > N) e0 = N;
    int s = 0;
    for (int i = b0 + threadIdx.x; i < e0; i += SCAN_T) s += deg[i];
    red[threadIdx.x] = s;
    __syncthreads();
    for (int off = SCAN_T / 2; off > 0; off >>= 1) {
        if (threadIdx.x < off) red[threadIdx.x] += red[threadIdx.x + off];
        __syncthreads();
    }
    if (threadIdx.x == 0) blksum[blockIdx.x] = red[0];
}

// k2: exclusive scan of the 64 block sums (tiny, serial is fine)
__global__ __launch_bounds__(64) void scan_blk(
    const int* __restrict__ blksum, int* __restrict__ blkoff)
{
    if (threadIdx.x == 0) {
        int acc = 0;
        for (int i = 0; i < SCAN_B; ++i) { blkoff[i] = acc; acc += blksum[i]; }
        blkoff[SCAN_B] = acc;
    }
}

// k3: per-block rescan writes row_ptr using blkoff base
__global__ __launch_bounds__(SCAN_T) void scan_final(
    const int* __restrict__ deg, const int* __restrict__ blkoff,
    int* __restrict__ row_ptr, int N)
{
    __shared__ int tsum[SCAN_T];
    int tid = threadIdx.x;
    int chunk = (N + SCAN_B - 1) / SCAN_B;
    int b0 = blockIdx.x * chunk;
    int e0 = b0 + chunk; if (e0 > N) e0 = N;
    int tchunk = (chunk + SCAN_T - 1) / SCAN_T;
    int tb = b0 + tid * tchunk;
    int te = tb + tchunk; if (te > e0) te = e0;
    int s = 0;
    for (int i = tb; i < te; ++i) s += deg[i];
    tsum[tid] = s;
    __syncthreads();
    for (int off = 1; off < SCAN_T; off <<= 1) {
        int v = (tid >= off) ? tsum[tid - off] : 0;
        __syncthreads();
        tsum[tid] += v;
        __syncthreads();
    }
    int base = blkoff[blockIdx.x] + ((tid == 0) ? 0 : tsum[tid - 1]);
    for (int i = tb; i < te; ++i) { row_ptr[i] = base; base += deg[i]; }
    if (blockIdx.x == SCAN_B - 1 && tid == SCAN_T - 1) row_ptr[N] = blkoff[SCAN_B];
}

__global__ __launch_bounds__(256) void csr_scatter(
    const int* __restrict__ srcv, const int* __restrict__ dstv,
    const int* __restrict__ etype, const float* __restrict__ ew,
    const int* __restrict__ row_ptr, int* __restrict__ cursor,
    int* __restrict__ c_src, int* __restrict__ c_et, float* __restrict__ c_ew,
    int E)
{
    int e = blockIdx.x * 256 + threadIdx.x;
    if (e >= E) return;
    int d = dstv[e];
    int p = row_ptr[d] + atomicAdd(&cursor[d], 1);
    c_src[p] = srcv[e];
    c_et[p]  = etype[e];
    c_ew[p]  = ew[e];
}

// ---------------------------------------------------------------------------
// Fused per-layer edge+softmax+aggregate+epilogue. One wave per dst node.
// Lane l owns channels {2l, 2l+1} (head h = l>>4). No atomics anywhere.
// ---------------------------------------------------------------------------
__global__ __launch_bounds__(256) void fused_conv(
    const int* __restrict__ row_ptr, const int* __restrict__ c_src,
    const int* __restrict__ c_et, const float* __restrict__ c_ew,
    const float* __restrict__ qs, const float* __restrict__ ks,
    const float* __restrict__ esum, const float* __restrict__ gate,
    const float* __restrict__ v, const float* __restrict__ bias,
    float* __restrict__ out, int N, int do_elu)
{
    int gw = (blockIdx.x * 256 + threadIdx.x) >> 6;   // global wave id = node
    int lane = threadIdx.x & 63;
    if (gw >= N) return;
    const int n = gw;
    const int beg = row_ptr[n], end = row_ptr[n + 1];
    const float4 qv = *(const float4*)&qs[(size_t)n * 4];
    const float4 gv = *(const float4*)gate;
    const int c0 = lane * 2;
    const int h = lane >> 4;          // head of channels 2l, 2l+1
    const float sc = 0.17677669529663687f;   // 1/sqrt(32)

    float num0 = 0.f, num1 = 0.f;
    float den0 = 0.f, den1 = 0.f, den2 = 0.f, den3 = 0.f;

    for (int j = beg; j < end; ++j) {
        int s   = c_src[j];
        int r   = c_et[j];
        float w = c_ew[j];
        float4 kv = *(const float4*)&ks[(size_t)s * 4];
        float4 ev = *(const float4*)&esum[(size_t)r * 4];
        float a0 = (qv.x + kv.x + ev.x) * sc + gv.x * w;
        float a1 = (qv.y + kv.y + ev.y) * sc + gv.y * w;
        float a2 = (qv.z + kv.z + ev.z) * sc + gv.z * w;
        float a3 = (qv.w + kv.w + ev.w) * sc + gv.w * w;
        a0 = a0 > 0.f ? a0 : 0.2f * a0;     // leaky_relu(0.2)
        a1 = a1 > 0.f ? a1 : 0.2f * a1;
        a2 = a2 > 0.f ? a2 : 0.2f * a2;
        a3 = a3 > 0.f ? a3 : 0.2f * a3;
        float e0 = __expf(a0), e1 = __expf(a1);
        float e2 = __expf(a2), e3 = __expf(a3);
        den0 += e0; den1 += e1; den2 += e2; den3 += e3;
        float ex = (h == 0) ? e0 : (h == 1) ? e1 : (h == 2) ? e2 : e3;
        float2 vv = *(const float2*)&v[(size_t)s * DD + c0];
        num0 += ex * vv.x;
        num1 += ex * vv.y;
    }

    float den = (h == 0) ? den0 : (h == 1) ? den1 : (h == 2) ? den2 : den3;
    float inv = 1.f / (den + 1e-16f);
    float r0 = num0 * inv + bias[c0];
    float r1 = num1 * inv + bias[c0 + 1];
    if (do_elu) {
        r0 = r0 > 0.f ? r0 : expm1f(r0);
        r1 = r1 > 0.f ? r1 : expm1f(r1);
    }
    *(float2*)&out[(size_t)n * DD + c0] = make_float2(r0, r1);
}

// ---------------------------------------------------------------------------
extern "C" void kernel_launch(void* const* d_in, const int* in_sizes, int n_in,
                              void* d_out, int out_size, void* d_ws, size_t ws_size,
                              hipStream_t stream)
{
    const int*   entity = (const int*)d_in[0];
    const int*   eidx   = (const int*)d_in[1];
    const int*   etype  = (const int*)d_in[2];
    const float* ew     = (const float*)d_in[3];
    const float* ent    = (const float*)d_in[4];
    const float* pw     = (const float*)d_in[5];
    const float* pb     = (const float*)d_in[6];
    const float* rel    = (const float*)d_in[7];
    const float* Wq     = (const float*)d_in[8];
    const float* Wk     = (const float*)d_in[9];
    const float* Wv     = (const float*)d_in[10];
    const float* We     = (const float*)d_in[11];
    const float* gate   = (const float*)d_in[12];
    const float* cb     = (const float*)d_in[13];

    const int N = in_sizes[0];
    const int E = in_sizes[2];
    const int F = in_sizes[4] / N;     // 256
    const int R = in_sizes[7] / DD;    // 200

    const int* srcv = eidx;
    const int* dstv = eidx + E;

    float* ws = (float*)d_ws;
    size_t o = 0;
    float* xbuf    = ws + o; o += (size_t)N * DD;
    float* vbuf    = ws + o; o += (size_t)N * DD;
    float* qs      = ws + o; o += (size_t)N * HD;
    float* ks      = ws + o; o += (size_t)N * HD;
    float* Wqh     = ws + o; o += 2 * DD * HD;
    float* Wkh     = ws + o; o += 2 * DD * HD;
    float* esum    = ws + o; o += (size_t)2 * R * HD;
    int*   deg     = (int*)(ws + o); o += N;
    int*   cursor  = (int*)(ws + o); o += N;
    int*   row_ptr = (int*)(ws + o); o += (size_t)N + 1;
    int*   blksum  = (int*)(ws + o); o += SCAN_B;
    int*   blkoff  = (int*)(ws + o); o += SCAN_B + 1;
    int*   c_src   = (int*)(ws + o); o += E;
    int*   c_et    = (int*)(ws + o); o += E;
    float* c_ew    = ws + o;         o += E;

    prep_kernel<<<1, 256, 0, stream>>>(Wq, Wk, We, rel, Wqh, Wkh, esum, R);

    // CSR build (layer-independent, built once)
    hipMemsetAsync(deg, 0, (size_t)2 * N * sizeof(int), stream);  // deg + cursor
    csr_count<<<(E + 255) / 256, 256, 0, stream>>>(dstv, deg, E);
    scan_partial<<<SCAN_B, SCAN_T, 0, stream>>>(deg, blksum, N);
    scan_blk<<<1, 64, 0, stream>>>(blksum, blkoff);
    scan_final<<<SCAN_B, SCAN_T, 0, stream>>>(deg, blkoff, row_ptr, N);
    csr_scatter<<<(E + 255) / 256, 256, 0, stream>>>(
        srcv, dstv, etype, ew, row_ptr, cursor, c_src, c_et, c_ew, E);

    const int gblk = (N + 63) / 64;
    // x0 = ent_table[entity] @ proj_w + proj_b
    gemm128<<<gblk, 256, 0, stream>>>(ent, entity, pw, pb, xbuf, N, F);

    const int fblk = (N + 3) / 4;     // one 64-lane wave per node
    for (int l = 0; l < 2; ++l) {
        gemm128<<<gblk, 256, 0, stream>>>(xbuf, nullptr, Wv + (size_t)l * DD * DD,
                                          nullptr, vbuf, N, DD);
        qk_sums<<<gblk, 256, 0, stream>>>(xbuf, Wqh + l * DD * HD, Wkh + l * DD * HD,
                                          qs, ks, N);
        fused_conv<<<fblk, 256, 0, stream>>>(
            row_ptr, c_src, c_et, c_ew, qs, ks, esum + (size_t)l * R * HD,
            gate + l * HD, vbuf, cb + l * DD,
            (l == 0) ? xbuf : (float*)d_out, N, (l == 0) ? 1 : 0);
    }
}

// Round 11
// 283.797 us; speedup vs baseline: 2.0608x; 1.2122x over previous
//
#include <hip/hip_runtime.h>

#define HD 4      // heads
#define DD 128    // model dim
#define CC 32     // channels per head
#define SCAN_B 64
#define SCAN_T 256

// ---------------------------------------------------------------------------
// Precompute per-head weight column-sums and per-relation esum table.
// Wqh[l*512 + d*4 + h] = sum_c Wq[l][d][h*32+c]   (same for Wkh)
// esum[(l*R + r)*4 + h] = rel_emb[r] . Weh[l][:,h]
// ---------------------------------------------------------------------------
__global__ __launch_bounds__(256) void prep_kernel(
    const float* __restrict__ Wq, const float* __restrict__ Wk,
    const float* __restrict__ We, const float* __restrict__ rel,
    float* __restrict__ Wqh, float* __restrict__ Wkh,
    float* __restrict__ esum, int R)
{
    __shared__ float WehS[2][DD][HD];   // 4 KB
    int tid = threadIdx.x;
    for (int i = tid; i < 2 * DD * HD; i += 256) {
        int l = i / (DD * HD);
        int d = (i / HD) % DD;
        int h = i % HD;
        const float* bq = Wq + ((size_t)l * DD + d) * DD + h * CC;
        const float* bk = Wk + ((size_t)l * DD + d) * DD + h * CC;
        const float* be = We + ((size_t)l * DD + d) * DD + h * CC;
        float sq = 0.f, sk = 0.f, se = 0.f;
        for (int c = 0; c < CC; ++c) { sq += bq[c]; sk += bk[c]; se += be[c]; }
        Wqh[i] = sq; Wkh[i] = sk; WehS[l][d][h] = se;
    }
    __syncthreads();
    for (int i = tid; i < 2 * R * HD; i += 256) {
        int l = i / (R * HD);
        int r = (i / HD) % R;
        int h = i % HD;
        const float* rp = rel + (size_t)r * DD;
        float a = 0.f;
        for (int d = 0; d < DD; ++d) a += rp[d] * WehS[l][d][h];
        esum[i] = a;
    }
}

// ---------------------------------------------------------------------------
// C[M x 128] = gather(A)[M x K] @ B[K x 128] (+bias). Tiled fp32 GEMM.
// (used for the input projection, K=256, gathered rows)
// ---------------------------------------------------------------------------
__global__ __launch_bounds__(256) void gemm128(
    const float* __restrict__ A, const int* __restrict__ gather,
    const float* __restrict__ B, const float* __restrict__ bias,
    float* __restrict__ C, int M, int K)
{
    __shared__ float As[16][68];
    __shared__ float Bs[16][132];
    const int tid = threadIdx.x;
    const int row0 = blockIdx.x * 64;
    const int ty = tid >> 5, tx = tid & 31;
    float acc[8][4] = {};

    const int ar = tid >> 2;
    const int ak = (tid & 3) * 4;
    int arow = row0 + ar; if (arow >= M) arow = M - 1;
    const int grow = gather ? gather[arow] : arow;
    const float* Ap = A + (size_t)grow * K;
    const int bk = tid >> 4;
    const int bc = (tid & 15) * 8;

    for (int k0 = 0; k0 < K; k0 += 16) {
        float4 av = *(const float4*)(Ap + k0 + ak);
        float4 b0 = *(const float4*)(B + (size_t)(k0 + bk) * DD + bc);
        float4 b1 = *(const float4*)(B + (size_t)(k0 + bk) * DD + bc + 4);
        __syncthreads();
        As[ak + 0][ar] = av.x; As[ak + 1][ar] = av.y;
        As[ak + 2][ar] = av.z; As[ak + 3][ar] = av.w;
        *(float4*)&Bs[bk][bc]     = b0;
        *(float4*)&Bs[bk][bc + 4] = b1;
        __syncthreads();
#pragma unroll
        for (int kk = 0; kk < 16; ++kk) {
            const float4 a0 = *(const float4*)&As[kk][ty * 8];
            const float4 a1 = *(const float4*)&As[kk][ty * 8 + 4];
            const float4 bv = *(const float4*)&Bs[kk][tx * 4];
            float a[8] = {a0.x, a0.y, a0.z, a0.w, a1.x, a1.y, a1.z, a1.w};
            float b[4] = {bv.x, bv.y, bv.z, bv.w};
#pragma unroll
            for (int i = 0; i < 8; ++i)
#pragma unroll
                for (int j = 0; j < 4; ++j) acc[i][j] += a[i] * b[j];
        }
    }
    float bv[4] = {0.f, 0.f, 0.f, 0.f};
    if (bias) {
        bv[0] = bias[tx * 4 + 0]; bv[1] = bias[tx * 4 + 1];
        bv[2] = bias[tx * 4 + 2]; bv[3] = bias[tx * 4 + 3];
    }
#pragma unroll
    for (int i = 0; i < 8; ++i) {
        int row = row0 + ty * 8 + i;
        if (row < M) {
            float4 r;
            r.x = acc[i][0] + bv[0]; r.y = acc[i][1] + bv[1];
            r.z = acc[i][2] + bv[2]; r.w = acc[i][3] + bv[3];
            *(float4*)&C[(size_t)row * DD + tx * 4] = r;
        }
    }
}

// ---------------------------------------------------------------------------
// Layer GEMM (K=128, no gather) with FUSED qs/ks computation: while the A
// tile registers are live, accumulate per-row per-head dot products with
// Wqh/Wkh; reduce across the 4 lanes sharing a row via shfl_xor.
// ---------------------------------------------------------------------------
__global__ __launch_bounds__(256) void gemm_v_qk(
    const float* __restrict__ A, const float* __restrict__ B,
    const float* __restrict__ Wqh, const float* __restrict__ Wkh,
    float* __restrict__ C, float* __restrict__ qs, float* __restrict__ ks,
    int M)
{
    __shared__ float As[16][68];
    __shared__ float Bs[16][132];
    __shared__ float wqS[DD * HD], wkS[DD * HD];   // 2 KB each
    const int tid = threadIdx.x;
    const int row0 = blockIdx.x * 64;
    const int ty = tid >> 5, tx = tid & 31;
    float acc[8][4] = {};
    float qp[4] = {}, kp[4] = {};

    for (int i = tid; i < DD * HD; i += 256) { wqS[i] = Wqh[i]; wkS[i] = Wkh[i]; }

    const int ar = tid >> 2;
    const int ak = (tid & 3) * 4;
    int arow = row0 + ar; if (arow >= M) arow = M - 1;
    const float* Ap = A + (size_t)arow * DD;
    const int bk = tid >> 4;
    const int bc = (tid & 15) * 8;

    for (int k0 = 0; k0 < DD; k0 += 16) {
        float4 av = *(const float4*)(Ap + k0 + ak);
        float4 b0 = *(const float4*)(B + (size_t)(k0 + bk) * DD + bc);
        float4 b1 = *(const float4*)(B + (size_t)(k0 + bk) * DD + bc + 4);
        __syncthreads();
        As[ak + 0][ar] = av.x; As[ak + 1][ar] = av.y;
        As[ak + 2][ar] = av.z; As[ak + 3][ar] = av.w;
        *(float4*)&Bs[bk][bc]     = b0;
        *(float4*)&Bs[bk][bc + 4] = b1;
        // fused qk partials from the A registers (no extra loads of x)
        float axr[4] = {av.x, av.y, av.z, av.w};
#pragma unroll
        for (int i = 0; i < 4; ++i) {
            int d = k0 + ak + i;
            float xv = axr[i];
#pragma unroll
            for (int h = 0; h < 4; ++h) {
                qp[h] += xv * wqS[d * HD + h];
                kp[h] += xv * wkS[d * HD + h];
            }
        }
        __syncthreads();
#pragma unroll
        for (int kk = 0; kk < 16; ++kk) {
            const float4 a0 = *(const float4*)&As[kk][ty * 8];
            const float4 a1 = *(const float4*)&As[kk][ty * 8 + 4];
            const float4 bv = *(const float4*)&Bs[kk][tx * 4];
            float a[8] = {a0.x, a0.y, a0.z, a0.w, a1.x, a1.y, a1.z, a1.w};
            float b[4] = {bv.x, bv.y, bv.z, bv.w};
#pragma unroll
            for (int i = 0; i < 8; ++i)
#pragma unroll
                for (int j = 0; j < 4; ++j) acc[i][j] += a[i] * b[j];
        }
    }

    // reduce qp/kp across the 4 consecutive lanes sharing row ar
#pragma unroll
    for (int off = 1; off < 4; off <<= 1) {
#pragma unroll
        for (int h = 0; h < 4; ++h) {
            qp[h] += __shfl_xor(qp[h], off, 64);
            kp[h] += __shfl_xor(kp[h], off, 64);
        }
    }
    if ((tid & 3) == 0) {
        int row = row0 + ar;
        if (row < M) {
            *(float4*)&qs[(size_t)row * HD] = make_float4(qp[0], qp[1], qp[2], qp[3]);
            *(float4*)&ks[(size_t)row * HD] = make_float4(kp[0], kp[1], kp[2], kp[3]);
        }
    }

#pragma unroll
    for (int i = 0; i < 8; ++i) {
        int row = row0 + ty * 8 + i;
        if (row < M) {
            float4 r;
            r.x = acc[i][0]; r.y = acc[i][1]; r.z = acc[i][2]; r.w = acc[i][3];
            *(float4*)&C[(size_t)row * DD + tx * 4] = r;
        }
    }
}

// ---------------------------------------------------------------------------
// CSR build: histogram + hierarchical 3-kernel scan + packed scatter.
// ---------------------------------------------------------------------------
__global__ __launch_bounds__(256) void csr_count(
    const int* __restrict__ dstv, int* __restrict__ deg, int E)
{
    int t = blockIdx.x * 256 + threadIdx.x;
    if (t < E) atomicAdd(&deg[dstv[t]], 1);
}

__global__ __launch_bounds__(SCAN_T) void scan_partial(
    const int* __restrict__ deg, int* __restrict__ blksum, int N)
{
    __shared__ int red[SCAN_T];
    int chunk = (N + SCAN_B - 1) / SCAN_B;
    int b0 = blockIdx.x * chunk;
    int e0 = b0 + chunk; if (e0 > N) e0 = N;
    int s = 0;
    for (int i = b0 + threadIdx.x; i < e0; i += SCAN_T) s += deg[i];
    red[threadIdx.x] = s;
    __syncthreads();
    for (int off = SCAN_T / 2; off > 0; off >>= 1) {
        if (threadIdx.x < off) red[threadIdx.x] += red[threadIdx.x + off];
        __syncthreads();
    }
    if (threadIdx.x == 0) blksum[blockIdx.x] = red[0];
}

__global__ __launch_bounds__(64) void scan_blk(
    const int* __restrict__ blksum, int* __restrict__ blkoff)
{
    if (threadIdx.x == 0) {
        int acc = 0;
        for (int i = 0; i < SCAN_B; ++i) { blkoff[i] = acc; acc += blksum[i]; }
        blkoff[SCAN_B] = acc;
    }
}

__global__ __launch_bounds__(SCAN_T) void scan_final(
    const int* __restrict__ deg, const int* __restrict__ blkoff,
    int* __restrict__ row_ptr, int N)
{
    __shared__ int tsum[SCAN_T];
    int tid = threadIdx.x;
    int chunk = (N + SCAN_B - 1) / SCAN_B;
    int b0 = blockIdx.x * chunk;
    int e0 = b0 + chunk; if (e0 > N) e0 = N;
    int tchunk = (chunk + SCAN_T - 1) / SCAN_T;
    int tb = b0 + tid * tchunk;
    int te = tb + tchunk; if (te > e0) te = e0;
    int s = 0;
    for (int i = tb; i < te; ++i) s += deg[i];
    tsum[tid] = s;
    __syncthreads();
    for (int off = 1; off < SCAN_T; off <<= 1) {
        int v = (tid >= off) ? tsum[tid - off] : 0;
        __syncthreads();
        tsum[tid] += v;
        __syncthreads();
    }
    int base = blkoff[blockIdx.x] + ((tid == 0) ? 0 : tsum[tid - 1]);
    for (int i = tb; i < te; ++i) { row_ptr[i] = base; base += deg[i]; }
    if (blockIdx.x == SCAN_B - 1 && tid == SCAN_T - 1) row_ptr[N] = blkoff[SCAN_B];
}

__global__ __launch_bounds__(256) void csr_scatter(
    const int* __restrict__ srcv, const int* __restrict__ dstv,
    const int* __restrict__ etype, const float* __restrict__ ew,
    const int* __restrict__ row_ptr, int* __restrict__ cursor,
    int4* __restrict__ c_pack, int E)
{
    int e = blockIdx.x * 256 + threadIdx.x;
    if (e >= E) return;
    int d = dstv[e];
    int p = row_ptr[d] + atomicAdd(&cursor[d], 1);
    c_pack[p] = make_int4(srcv[e], etype[e], __float_as_int(ew[e]), 0);
}

// ---------------------------------------------------------------------------
// Fused per-layer edge+softmax+aggregate+epilogue. One wave per dst node.
// Lane l owns channels {2l, 2l+1}; head h = l>>4. Each lane computes ONLY
// its own head's alpha chain (den identical across a head's 16 lanes).
// Packed int4 edge record, software-prefetched. No atomics.
// ---------------------------------------------------------------------------
__global__ __launch_bounds__(256) void fused_conv(
    const int* __restrict__ row_ptr, const int4* __restrict__ c_pack,
    const float* __restrict__ qs, const float* __restrict__ ks,
    const float* __restrict__ esum, const float* __restrict__ gate,
    const float* __restrict__ v, const float* __restrict__ bias,
    float* __restrict__ out, int N, int do_elu)
{
    int gw = (blockIdx.x * 256 + threadIdx.x) >> 6;   // global wave id = node
    int lane = threadIdx.x & 63;
    if (gw >= N) return;
    const int n = gw;
    const int beg = row_ptr[n], end = row_ptr[n + 1];
    const int c0 = lane * 2;
    const int h = lane >> 4;          // head of channels 2l, 2l+1
    const float qh = qs[(size_t)n * HD + h];
    const float gh = gate[h];
    const float sc = 0.17677669529663687f;   // 1/sqrt(32)

    float num0 = 0.f, num1 = 0.f, den = 0.f;

    int j = beg;
    int4 p;
    if (j < end) p = c_pack[j];
    while (j < end) {
        int4 cur = p;
        ++j;
        if (j < end) p = c_pack[j];           // prefetch next record
        int s = cur.x, r = cur.y;
        float w = __int_as_float(cur.z);
        float kh = ks[(size_t)s * HD + h];
        float eh = esum[(size_t)r * HD + h];
        float2 vv = *(const float2*)&v[(size_t)s * DD + c0];
        float a = (qh + kh + eh) * sc + gh * w;
        a = a > 0.f ? a : 0.2f * a;           // leaky_relu(0.2)
        float e = __expf(a);
        den += e;
        num0 = fmaf(e, vv.x, num0);
        num1 = fmaf(e, vv.y, num1);
    }

    float inv = 1.f / (den + 1e-16f);
    float r0 = num0 * inv + bias[c0];
    float r1 = num1 * inv + bias[c0 + 1];
    if (do_elu) {
        r0 = r0 > 0.f ? r0 : expm1f(r0);
        r1 = r1 > 0.f ? r1 : expm1f(r1);
    }
    *(float2*)&out[(size_t)n * DD + c0] = make_float2(r0, r1);
}

// ---------------------------------------------------------------------------
extern "C" void kernel_launch(void* const* d_in, const int* in_sizes, int n_in,
                              void* d_out, int out_size, void* d_ws, size_t ws_size,
                              hipStream_t stream)
{
    const int*   entity = (const int*)d_in[0];
    const int*   eidx   = (const int*)d_in[1];
    const int*   etype  = (const int*)d_in[2];
    const float* ew     = (const float*)d_in[3];
    const float* ent    = (const float*)d_in[4];
    const float* pw     = (const float*)d_in[5];
    const float* pb     = (const float*)d_in[6];
    const float* rel    = (const float*)d_in[7];
    const float* Wq     = (const float*)d_in[8];
    const float* Wk     = (const float*)d_in[9];
    const float* Wv     = (const float*)d_in[10];
    const float* We     = (const float*)d_in[11];
    const float* gate   = (const float*)d_in[12];
    const float* cb     = (const float*)d_in[13];

    const int N = in_sizes[0];
    const int E = in_sizes[2];
    const int F = in_sizes[4] / N;     // 256
    const int R = in_sizes[7] / DD;    // 200

    const int* srcv = eidx;
    const int* dstv = eidx + E;

    float* ws = (float*)d_ws;
    size_t o = 0;
    float* xbuf    = ws + o; o += (size_t)N * DD;
    float* vbuf    = ws + o; o += (size_t)N * DD;
    float* qs      = ws + o; o += (size_t)N * HD;
    float* ks      = ws + o; o += (size_t)N * HD;
    float* Wqh     = ws + o; o += 2 * DD * HD;
    float* Wkh     = ws + o; o += 2 * DD * HD;
    float* esum    = ws + o; o += (size_t)2 * R * HD;
    int*   deg     = (int*)(ws + o); o += N;
    int*   cursor  = (int*)(ws + o); o += N;
    int*   row_ptr = (int*)(ws + o); o += (size_t)N + 1;
    int*   blksum  = (int*)(ws + o); o += SCAN_B;
    int*   blkoff  = (int*)(ws + o); o += SCAN_B + 1;
    o = (o + 3) & ~(size_t)3;                       // 16B-align c_pack
    int4*  c_pack  = (int4*)(ws + o); o += (size_t)E * 4;

    prep_kernel<<<1, 256, 0, stream>>>(Wq, Wk, We, rel, Wqh, Wkh, esum, R);

    // CSR build (layer-independent, built once)
    hipMemsetAsync(deg, 0, (size_t)2 * N * sizeof(int), stream);  // deg + cursor
    csr_count<<<(E + 255) / 256, 256, 0, stream>>>(dstv, deg, E);
    scan_partial<<<SCAN_B, SCAN_T, 0, stream>>>(deg, blksum, N);
    scan_blk<<<1, 64, 0, stream>>>(blksum, blkoff);
    scan_final<<<SCAN_B, SCAN_T, 0, stream>>>(deg, blkoff, row_ptr, N);
    csr_scatter<<<(E + 255) / 256, 256, 0, stream>>>(
        srcv, dstv, etype, ew, row_ptr, cursor, c_pack, E);

    const int gblk = (N + 63) / 64;
    // x0 = ent_table[entity] @ proj_w + proj_b
    gemm128<<<gblk, 256, 0, stream>>>(ent, entity, pw, pb, xbuf, N, F);

    const int fblk = (N + 3) / 4;     // one 64-lane wave per node
    for (int l = 0; l < 2; ++l) {
        gemm_v_qk<<<gblk, 256, 0, stream>>>(
            xbuf, Wv + (size_t)l * DD * DD, Wqh + l * DD * HD, Wkh + l * DD * HD,
            vbuf, qs, ks, N);
        fused_conv<<<fblk, 256, 0, stream>>>(
            row_ptr, c_pack, qs, ks, esum + (size_t)l * R * HD,
            gate + l * HD, vbuf, cb + l * DD,
            (l == 0) ? xbuf : (float*)d_out, N, (l == 0) ? 1 : 0);
    }
}